// Round 1
// baseline (2470.710 us; speedup 1.0000x reference)
//
#include <hip/hip_runtime.h>

typedef unsigned short u16;
using bf16x8 = __attribute__((ext_vector_type(8))) __bf16;
using f32x4  = __attribute__((ext_vector_type(4))) float;

__device__ __forceinline__ u16 f2b(float f) {
    unsigned u = __float_as_uint(f);
    u += 0x7fffu + ((u >> 16) & 1u);   // round-to-nearest-even
    return (u16)(u >> 16);
}
__device__ __forceinline__ float b2f(u16 h) {
    return __uint_as_float(((unsigned)h) << 16);
}
__device__ __forceinline__ float loadx(const float* __restrict__ p, size_t i) { return p[i]; }
__device__ __forceinline__ float loadx(const u16* __restrict__ p, size_t i) { return b2f(p[i]); }

// async global->LDS, 16B per lane; LDS dest = wave-uniform base + lane*16
__device__ __forceinline__ void gl2lds16(const void* g, void* l) {
    __builtin_amdgcn_global_load_lds(
        (const __attribute__((address_space(1))) void*)g,
        (__attribute__((address_space(3))) void*)l, 16, 0, 0);
}

// ---------------------------------------------------------------- elementwise
__global__ __launch_bounds__(256) void cast_bf16_kernel(
        const float4* __restrict__ src, ushort4* __restrict__ dst, int n4) {
    int i = blockIdx.x * 256 + threadIdx.x;
    if (i < n4) {
        float4 v = src[i];
        ushort4 o; o.x = f2b(v.x); o.y = f2b(v.y); o.z = f2b(v.z); o.w = f2b(v.w);
        dst[i] = o;
    }
}

__global__ __launch_bounds__(256) void prec2_kernel(
        const float* __restrict__ lp, float* __restrict__ p2, int n) {
    int i = blockIdx.x * 256 + threadIdx.x;
    if (i < n) {
        float v = lp[i];
        float sp = fmaxf(v, 0.f) + log1pf(expf(-fabsf(v)));   // stable softplus
        p2[i] = sp * sp;
    }
}

// src[R][C] f32 -> dst[C][R] bf16
__global__ __launch_bounds__(256) void transpose_cast_kernel(
        const float* __restrict__ src, u16* __restrict__ dst, int R, int C) {
    __shared__ float tile[32][33];
    const int bx = blockIdx.x * 32;      // col block in src
    const int by = blockIdx.y * 32;      // row block in src
    const int tx = threadIdx.x & 31;
    const int ty = threadIdx.x >> 5;     // 0..7
#pragma unroll
    for (int i = 0; i < 32; i += 8)
        tile[ty + i][tx] = src[(size_t)(by + ty + i) * C + (bx + tx)];
    __syncthreads();
#pragma unroll
    for (int i = 0; i < 32; i += 8)
        dst[(size_t)(bx + ty + i) * R + (by + tx)] = f2b(tile[tx][ty + i]);
}

// ---------------------------------------------------------------- layernorm
// one block (256 thr) per row; T fp32 [B,D] -> out (bf16 or f32), D in {1024,2048}
template <int F32OUT>
__global__ __launch_bounds__(256) void ln_kernel(
        const float* __restrict__ T, const float* __restrict__ g,
        const float* __restrict__ b, void* __restrict__ outp, int D) {
    const int row = blockIdx.x;
    const int tid = threadIdx.x;
    const int nv  = D >> 2;
    const float4* rp = (const float4*)(T + (size_t)row * D);

    float4 vals[2];
    float s = 0.f, sq = 0.f;
    int cnt = 0;
    for (int i = tid; i < nv; i += 256) {
        float4 v = rp[i];
        vals[cnt++] = v;
        s  += v.x + v.y + v.z + v.w;
        sq += v.x * v.x + v.y * v.y + v.z * v.z + v.w * v.w;
    }
#pragma unroll
    for (int off = 32; off > 0; off >>= 1) {
        s  += __shfl_down(s, off);
        sq += __shfl_down(sq, off);
    }
    __shared__ float ssum[4], ssq[4];
    if ((tid & 63) == 0) { ssum[tid >> 6] = s; ssq[tid >> 6] = sq; }
    __syncthreads();
    const float ts = ssum[0] + ssum[1] + ssum[2] + ssum[3];
    const float tq = ssq[0] + ssq[1] + ssq[2] + ssq[3];
    const float mu   = ts / (float)D;
    const float rstd = rsqrtf(tq / (float)D - mu * mu + 1e-5f);

    cnt = 0;
    for (int i = tid; i < nv; i += 256) {
        float4 v  = vals[cnt++];
        float4 gg = ((const float4*)g)[i];
        float4 bb = ((const float4*)b)[i];
        float o0 = (v.x - mu) * rstd * gg.x + bb.x;
        float o1 = (v.y - mu) * rstd * gg.y + bb.y;
        float o2 = (v.z - mu) * rstd * gg.z + bb.z;
        float o3 = (v.w - mu) * rstd * gg.w + bb.w;
        if (F32OUT) {
            ((float4*)outp)[(size_t)row * nv + i] = make_float4(o0, o1, o2, o3);
        } else {
            ushort4 o; o.x = f2b(o0); o.y = f2b(o1); o.z = f2b(o2); o.w = f2b(o3);
            ((ushort4*)outp)[(size_t)row * nv + i] = o;
        }
    }
}

// ---------------------------------------------------------------- GEMM
// C[M,N] = A[M,K] (bf16, row-major) x Bt[N,K]^T (bf16, row-major [N,K])
// m97 structure: 128x128 tile, BK=32, 4 waves (2x2), 4x4 mfma_16x16x32_bf16 each.
// Epilogues:
//   EPI_BIAS: out_f32 = acc + bias[n]
//   EPI_ERR : out_bf16 = (X[m,n] - (acc + bias[n])) * p2[n]
//   EPI_H   : out_f32 = bf2f(H[m,n]) + 0.2f * acc
enum { EPI_BIAS = 0, EPI_ERR = 1, EPI_H = 2 };

template <int EPI, typename XT>
__global__ __launch_bounds__(256) void gemm_bt(
        const u16* __restrict__ A, const u16* __restrict__ Bt, int N, int K,
        const float* __restrict__ bias, const float* __restrict__ p2,
        const XT* __restrict__ X, const u16* __restrict__ H,
        void* __restrict__ outp) {
    __shared__ u16 As[128 * 32];
    __shared__ u16 Bs[128 * 32];

    const int tid  = threadIdx.x;
    const int lane = tid & 63;
    const int wave = tid >> 6;
    const size_t row0 = (size_t)blockIdx.y * 128;
    const size_t col0 = (size_t)blockIdx.x * 128;

    // staging: 256 lanes x 16B = 64 rows x 32 bf16 per issue; 2 issues per tile
    const int sr = tid >> 2;          // row within issue
    const int sc = (tid & 3) * 8;     // k offset (elements)
    const u16* gA0 = A  + (row0 + sr) * K + sc;
    const u16* gA1 = gA0 + (size_t)64 * K;
    const u16* gB0 = Bt + (col0 + sr) * K + sc;
    const u16* gB1 = gB0 + (size_t)64 * K;
    char* lA = (char*)As + wave * 1024;   // wave-uniform LDS base
    char* lB = (char*)Bs + wave * 1024;

    const int wm = wave >> 1, wn = wave & 1;
    const int fr = lane & 15;
    const int fq = lane >> 4;
    const bf16x8* aP[4];
    const bf16x8* bP[4];
#pragma unroll
    for (int i = 0; i < 4; ++i) {
        aP[i] = (const bf16x8*)(As + (wm * 64 + i * 16 + fr) * 32 + fq * 8);
        bP[i] = (const bf16x8*)(Bs + (wn * 64 + i * 16 + fr) * 32 + fq * 8);
    }

    f32x4 acc[4][4];
    const f32x4 zero = {0.f, 0.f, 0.f, 0.f};
#pragma unroll
    for (int i = 0; i < 4; ++i)
#pragma unroll
        for (int j = 0; j < 4; ++j) acc[i][j] = zero;

    for (int k0 = 0; k0 < K; k0 += 32) {
        __syncthreads();
        gl2lds16(gA0, lA);
        gl2lds16(gA1, lA + 4096);
        gl2lds16(gB0, lB);
        gl2lds16(gB1, lB + 4096);
        __syncthreads();
        bf16x8 af[4], bfr[4];
#pragma unroll
        for (int i = 0; i < 4; ++i) { af[i] = *aP[i]; bfr[i] = *bP[i]; }
#pragma unroll
        for (int i = 0; i < 4; ++i)
#pragma unroll
            for (int j = 0; j < 4; ++j)
                acc[i][j] = __builtin_amdgcn_mfma_f32_16x16x32_bf16(
                    af[i], bfr[j], acc[i][j], 0, 0, 0);
        gA0 += 32; gA1 += 32; gB0 += 32; gB1 += 32;
    }

    // epilogue: C/D layout col = lane&15, row = (lane>>4)*4 + reg
#pragma unroll
    for (int i = 0; i < 4; ++i) {
#pragma unroll
        for (int r = 0; r < 4; ++r) {
            const size_t gr = row0 + wm * 64 + i * 16 + fq * 4 + r;
#pragma unroll
            for (int j = 0; j < 4; ++j) {
                const size_t gc  = col0 + wn * 64 + j * 16 + fr;
                const size_t idx = gr * (size_t)N + gc;
                const float v = acc[i][j][r];
                if (EPI == EPI_BIAS) {
                    ((float*)outp)[idx] = v + bias[gc];
                } else if (EPI == EPI_ERR) {
                    const float e = (loadx(X, idx) - (v + bias[gc])) * p2[gc];
                    ((u16*)outp)[idx] = f2b(e);
                } else {
                    ((float*)outp)[idx] = b2f(H[idx]) + 0.2f * v;
                }
            }
        }
    }
}

// ---------------------------------------------------------------- host
extern "C" void kernel_launch(void* const* d_in, const int* in_sizes, int n_in,
                              void* d_out, int out_size, void* d_ws, size_t ws_size,
                              hipStream_t stream) {
    const int B = 8192;
    const float* x      = (const float*)d_in[0];
    const float* gen_w0 = (const float*)d_in[1];
    const float* gen_b0 = (const float*)d_in[2];
    const float* rec_w0 = (const float*)d_in[3];
    const float* rec_b0 = (const float*)d_in[4];
    const float* log_p0 = (const float*)d_in[5];
    const float* ln_g0  = (const float*)d_in[6];
    const float* ln_b0  = (const float*)d_in[7];
    const float* gen_w1 = (const float*)d_in[8];
    const float* gen_b1 = (const float*)d_in[9];
    const float* rec_w1 = (const float*)d_in[10];
    const float* rec_b1 = (const float*)d_in[11];
    const float* log_p1 = (const float*)d_in[12];
    const float* ln_g1  = (const float*)d_in[13];
    const float* ln_b1  = (const float*)d_in[14];

    char* ws = (char*)d_ws;
    auto alloc = [&](size_t bytes) -> char* {
        char* p = ws;
        ws += (bytes + 255) & ~(size_t)255;
        return p;
    };
    u16*   Eb    = (u16*)  alloc((size_t)B * 4096 * 2);   // err buf; aliases Xb
    float* Tf    = (float*)alloc((size_t)B * 2048 * 4);   // pre-LN fp32
    u16*   Hb0   = (u16*)  alloc((size_t)B * 2048 * 2);
    u16*   Hb1   = (u16*)  alloc((size_t)B * 1024 * 2);
    u16*   rwb0  = (u16*)  alloc((size_t)2048 * 4096 * 2);
    u16*   gwb0  = (u16*)  alloc((size_t)4096 * 2048 * 2);
    u16*   gwtb0 = (u16*)  alloc((size_t)2048 * 4096 * 2);
    u16*   rwb1  = (u16*)  alloc((size_t)1024 * 2048 * 2);
    u16*   gwb1  = (u16*)  alloc((size_t)2048 * 1024 * 2);
    u16*   gwtb1 = (u16*)  alloc((size_t)1024 * 2048 * 2);
    float* p20   = (float*)alloc(4096 * 4);
    float* p21   = (float*)alloc(2048 * 4);
    u16*   Xb    = Eb;   // x_bf16 only needed before first err write

    auto cast = [&](const float* s, u16* d, size_t n) {
        int n4 = (int)(n >> 2);
        cast_bf16_kernel<<<dim3((n4 + 255) / 256), dim3(256), 0, stream>>>(
            (const float4*)s, (ushort4*)d, n4);
    };

    // ---- pre-pass: casts / transposes / prec2
    cast(x, Xb, (size_t)B * 4096);
    cast(rec_w0, rwb0, (size_t)2048 * 4096);
    cast(gen_w0, gwb0, (size_t)4096 * 2048);
    transpose_cast_kernel<<<dim3(2048 / 32, 4096 / 32), dim3(256), 0, stream>>>(
        gen_w0, gwtb0, 4096, 2048);
    cast(rec_w1, rwb1, (size_t)1024 * 2048);
    cast(gen_w1, gwb1, (size_t)2048 * 1024);
    transpose_cast_kernel<<<dim3(1024 / 32, 2048 / 32), dim3(256), 0, stream>>>(
        gen_w1, gwtb1, 2048, 1024);
    prec2_kernel<<<dim3(16), dim3(256), 0, stream>>>(log_p0, p20, 4096);
    prec2_kernel<<<dim3(8), dim3(256), 0, stream>>>(log_p1, p21, 2048);

    const dim3 blk(256);

    // ---- layer 0 (in=4096, hid=2048)
    gemm_bt<EPI_BIAS, float><<<dim3(2048 / 128, B / 128), blk, 0, stream>>>(
        Xb, rwb0, 2048, 4096, rec_b0, nullptr, (const float*)nullptr, nullptr, Tf);
    ln_kernel<0><<<dim3(B), blk, 0, stream>>>(Tf, ln_g0, ln_b0, Hb0, 2048);
    for (int it = 0; it < 3; ++it) {
        gemm_bt<EPI_ERR, float><<<dim3(4096 / 128, B / 128), blk, 0, stream>>>(
            Hb0, gwb0, 4096, 2048, gen_b0, p20, x, nullptr, Eb);
        gemm_bt<EPI_H, float><<<dim3(2048 / 128, B / 128), blk, 0, stream>>>(
            Eb, gwtb0, 2048, 4096, nullptr, nullptr, (const float*)nullptr, Hb0, Tf);
        ln_kernel<0><<<dim3(B), blk, 0, stream>>>(Tf, ln_g0, ln_b0, Hb0, 2048);
    }

    // ---- layer 1 (in=2048, hid=1024); input x = Hb0 (bf16)
    gemm_bt<EPI_BIAS, float><<<dim3(1024 / 128, B / 128), blk, 0, stream>>>(
        Hb0, rwb1, 1024, 2048, rec_b1, nullptr, (const float*)nullptr, nullptr, Tf);
    ln_kernel<0><<<dim3(B), blk, 0, stream>>>(Tf, ln_g1, ln_b1, Hb1, 1024);
    for (int it = 0; it < 3; ++it) {
        gemm_bt<EPI_ERR, u16><<<dim3(2048 / 128, B / 128), blk, 0, stream>>>(
            Hb1, gwb1, 2048, 1024, gen_b1, p21, Hb0, nullptr, Eb);
        gemm_bt<EPI_H, float><<<dim3(1024 / 128, B / 128), blk, 0, stream>>>(
            Eb, gwtb1, 1024, 2048, nullptr, nullptr, (const float*)nullptr, Hb1, Tf);
        if (it < 2)
            ln_kernel<0><<<dim3(B), blk, 0, stream>>>(Tf, ln_g1, ln_b1, Hb1, 1024);
        else
            ln_kernel<1><<<dim3(B), blk, 0, stream>>>(Tf, ln_g1, ln_b1, d_out, 1024);
    }
}

// Round 2
// 1641.399 us; speedup vs baseline: 1.5052x; 1.5052x over previous
//
#include <hip/hip_runtime.h>

typedef unsigned short u16;
using bf16x8 = __attribute__((ext_vector_type(8))) __bf16;
using f32x4  = __attribute__((ext_vector_type(4))) float;

__device__ __forceinline__ u16 f2b(float f) {
    unsigned u = __float_as_uint(f);
    u += 0x7fffu + ((u >> 16) & 1u);   // round-to-nearest-even
    return (u16)(u >> 16);
}
__device__ __forceinline__ float b2f(u16 h) {
    return __uint_as_float(((unsigned)h) << 16);
}

// async global->LDS, 16B per lane; LDS dest = wave-uniform base + lane*16
__device__ __forceinline__ void gl2lds16(const void* g, void* l) {
    __builtin_amdgcn_global_load_lds(
        (const __attribute__((address_space(1))) void*)g,
        (__attribute__((address_space(3))) void*)l, 16, 0, 0);
}

// ---------------------------------------------------------------- elementwise
__global__ __launch_bounds__(256) void cast_bf16_kernel(
        const float4* __restrict__ src, ushort4* __restrict__ dst, int n4) {
    int i = blockIdx.x * 256 + threadIdx.x;
    if (i < n4) {
        float4 v = src[i];
        ushort4 o; o.x = f2b(v.x); o.y = f2b(v.y); o.z = f2b(v.z); o.w = f2b(v.w);
        dst[i] = o;
    }
}

__global__ __launch_bounds__(256) void prec2_kernel(
        const float* __restrict__ lp, float* __restrict__ p2, int n) {
    int i = blockIdx.x * 256 + threadIdx.x;
    if (i < n) {
        float v = lp[i];
        float sp = fmaxf(v, 0.f) + log1pf(expf(-fabsf(v)));   // stable softplus
        p2[i] = sp * sp;
    }
}

// src[R][C] f32 -> dst[C][R] bf16, optionally scaled by scale[src_row]
__global__ __launch_bounds__(256) void transpose_cast_kernel(
        const float* __restrict__ src, u16* __restrict__ dst, int R, int C,
        const float* __restrict__ scale) {
    __shared__ float tile[32][33];
    const int bx = blockIdx.x * 32;      // col block in src
    const int by = blockIdx.y * 32;      // row block in src
    const int tx = threadIdx.x & 31;
    const int ty = threadIdx.x >> 5;     // 0..7
#pragma unroll
    for (int i = 0; i < 32; i += 8) {
        float s = scale ? scale[by + ty + i] : 1.f;
        tile[ty + i][tx] = s * src[(size_t)(by + ty + i) * C + (bx + tx)];
    }
    __syncthreads();
#pragma unroll
    for (int i = 0; i < 32; i += 8)
        dst[(size_t)(bx + ty + i) * R + (by + tx)] = f2b(tile[tx][ty + i]);
}

// cvec[j] = sum_i gb[i] * DGt[j][i]; one wave per j
__global__ __launch_bounds__(256) void cvec_kernel(
        const float* __restrict__ gb, const u16* __restrict__ DGt,
        float* __restrict__ cv, int in) {
    const int j = blockIdx.x * 4 + (threadIdx.x >> 6);
    const int lane = threadIdx.x & 63;
    const u16* row = DGt + (size_t)j * in;
    float s = 0.f;
    for (int i = lane; i < in; i += 64) s += gb[i] * b2f(row[i]);
#pragma unroll
    for (int off = 32; off > 0; off >>= 1) s += __shfl_down(s, off);
    if (lane == 0) cv[j] = s;
}

// ---------------------------------------------------------------- layernorm
// one block (256 thr) per row; T fp32 [B,D] -> out (bf16 or f32), D in {1024,2048}
template <int F32OUT>
__global__ __launch_bounds__(256) void ln_kernel(
        const float* __restrict__ T, const float* __restrict__ g,
        const float* __restrict__ b, void* __restrict__ outp, int D) {
    const int row = blockIdx.x;
    const int tid = threadIdx.x;
    const int nv  = D >> 2;
    const float4* rp = (const float4*)(T + (size_t)row * D);

    float4 vals[2];
    float s = 0.f, sq = 0.f;
    int cnt = 0;
    for (int i = tid; i < nv; i += 256) {
        float4 v = rp[i];
        vals[cnt++] = v;
        s  += v.x + v.y + v.z + v.w;
        sq += v.x * v.x + v.y * v.y + v.z * v.z + v.w * v.w;
    }
#pragma unroll
    for (int off = 32; off > 0; off >>= 1) {
        s  += __shfl_down(s, off);
        sq += __shfl_down(sq, off);
    }
    __shared__ float ssum[4], ssq[4];
    if ((tid & 63) == 0) { ssum[tid >> 6] = s; ssq[tid >> 6] = sq; }
    __syncthreads();
    const float ts = ssum[0] + ssum[1] + ssum[2] + ssum[3];
    const float tq = ssq[0] + ssq[1] + ssq[2] + ssq[3];
    const float mu   = ts / (float)D;
    const float rstd = rsqrtf(tq / (float)D - mu * mu + 1e-5f);

    cnt = 0;
    for (int i = tid; i < nv; i += 256) {
        float4 v  = vals[cnt++];
        float4 gg = ((const float4*)g)[i];
        float4 bb = ((const float4*)b)[i];
        float o0 = (v.x - mu) * rstd * gg.x + bb.x;
        float o1 = (v.y - mu) * rstd * gg.y + bb.y;
        float o2 = (v.z - mu) * rstd * gg.z + bb.z;
        float o3 = (v.w - mu) * rstd * gg.w + bb.w;
        if (F32OUT) {
            ((float4*)outp)[(size_t)row * nv + i] = make_float4(o0, o1, o2, o3);
        } else {
            ushort4 o; o.x = f2b(o0); o.y = f2b(o1); o.z = f2b(o2); o.w = f2b(o3);
            ((ushort4*)outp)[(size_t)row * nv + i] = o;
        }
    }
}

// ---------------------------------------------------------------- GEMM
// C[M,N] = A[M,K] (bf16, row-major) x Bt[N,K]^T (bf16, row-major [N,K])
// m97 structure: 128x128 tile, BK=32, 4 waves (2x2), 4x4 mfma_16x16x32_bf16 each.
// Epilogues:
//   EPI_BIAS: out_f32  = acc + bias[n]                        (rec pass)
//   EPI_CMB : out_bf16 = acc - bias[n]                        (c = x@DG - cvec)
//   EPI_W   : out_bf16 = acc                                  (W = G^T D G)
//   EPI_ITER: out_f32  = bf(H) + 0.2*(bf(Cc) - acc)           (h update)
enum { EPI_BIAS = 0, EPI_CMB = 1, EPI_W = 2, EPI_ITER = 3 };

template <int EPI>
__global__ __launch_bounds__(256) void gemm_bt(
        const u16* __restrict__ A, const u16* __restrict__ Bt, int N, int K,
        const float* __restrict__ bias, const u16* __restrict__ Cc,
        const u16* __restrict__ H, void* __restrict__ outp) {
    __shared__ u16 As[128 * 32];
    __shared__ u16 Bs[128 * 32];

    const int tid  = threadIdx.x;
    const int lane = tid & 63;
    const int wave = tid >> 6;
    const size_t row0 = (size_t)blockIdx.y * 128;
    const size_t col0 = (size_t)blockIdx.x * 128;

    // staging: 256 lanes x 16B = 64 rows x 32 bf16 per issue; 2 issues per tile
    const int sr = tid >> 2;          // row within issue
    const int sc = (tid & 3) * 8;     // k offset (elements)
    const u16* gA0 = A  + (row0 + sr) * K + sc;
    const u16* gA1 = gA0 + (size_t)64 * K;
    const u16* gB0 = Bt + (col0 + sr) * K + sc;
    const u16* gB1 = gB0 + (size_t)64 * K;
    char* lA = (char*)As + wave * 1024;   // wave-uniform LDS base
    char* lB = (char*)Bs + wave * 1024;

    const int wm = wave >> 1, wn = wave & 1;
    const int fr = lane & 15;
    const int fq = lane >> 4;
    const bf16x8* aP[4];
    const bf16x8* bP[4];
#pragma unroll
    for (int i = 0; i < 4; ++i) {
        aP[i] = (const bf16x8*)(As + (wm * 64 + i * 16 + fr) * 32 + fq * 8);
        bP[i] = (const bf16x8*)(Bs + (wn * 64 + i * 16 + fr) * 32 + fq * 8);
    }

    f32x4 acc[4][4];
    const f32x4 zero = {0.f, 0.f, 0.f, 0.f};
#pragma unroll
    for (int i = 0; i < 4; ++i)
#pragma unroll
        for (int j = 0; j < 4; ++j) acc[i][j] = zero;

    for (int k0 = 0; k0 < K; k0 += 32) {
        __syncthreads();
        gl2lds16(gA0, lA);
        gl2lds16(gA1, lA + 4096);
        gl2lds16(gB0, lB);
        gl2lds16(gB1, lB + 4096);
        __syncthreads();
        bf16x8 af[4], bfr[4];
#pragma unroll
        for (int i = 0; i < 4; ++i) { af[i] = *aP[i]; bfr[i] = *bP[i]; }
#pragma unroll
        for (int i = 0; i < 4; ++i)
#pragma unroll
            for (int j = 0; j < 4; ++j)
                acc[i][j] = __builtin_amdgcn_mfma_f32_16x16x32_bf16(
                    af[i], bfr[j], acc[i][j], 0, 0, 0);
        gA0 += 32; gA1 += 32; gB0 += 32; gB1 += 32;
    }

    // epilogue: C/D layout col = lane&15, row = (lane>>4)*4 + reg
#pragma unroll
    for (int i = 0; i < 4; ++i) {
#pragma unroll
        for (int r = 0; r < 4; ++r) {
            const size_t gr = row0 + wm * 64 + i * 16 + fq * 4 + r;
#pragma unroll
            for (int j = 0; j < 4; ++j) {
                const size_t gc  = col0 + wn * 64 + j * 16 + fr;
                const size_t idx = gr * (size_t)N + gc;
                const float v = acc[i][j][r];
                if (EPI == EPI_BIAS) {
                    ((float*)outp)[idx] = v + bias[gc];
                } else if (EPI == EPI_CMB) {
                    ((u16*)outp)[idx] = f2b(v - bias[gc]);
                } else if (EPI == EPI_W) {
                    ((u16*)outp)[idx] = f2b(v);
                } else {
                    ((float*)outp)[idx] = b2f(H[idx]) + 0.2f * (b2f(Cc[idx]) - v);
                }
            }
        }
    }
}

// ---------------------------------------------------------------- host
extern "C" void kernel_launch(void* const* d_in, const int* in_sizes, int n_in,
                              void* d_out, int out_size, void* d_ws, size_t ws_size,
                              hipStream_t stream) {
    const int B = 8192;
    const float* x      = (const float*)d_in[0];
    const float* gen_w0 = (const float*)d_in[1];
    const float* gen_b0 = (const float*)d_in[2];
    const float* rec_w0 = (const float*)d_in[3];
    const float* rec_b0 = (const float*)d_in[4];
    const float* log_p0 = (const float*)d_in[5];
    const float* ln_g0  = (const float*)d_in[6];
    const float* ln_b0  = (const float*)d_in[7];
    const float* gen_w1 = (const float*)d_in[8];
    const float* gen_b1 = (const float*)d_in[9];
    const float* rec_w1 = (const float*)d_in[10];
    const float* rec_b1 = (const float*)d_in[11];
    const float* log_p1 = (const float*)d_in[12];
    const float* ln_g1  = (const float*)d_in[13];
    const float* ln_b1  = (const float*)d_in[14];

    char* ws = (char*)d_ws;
    auto alloc = [&](size_t bytes) -> char* {
        char* p = ws;
        ws += (bytes + 255) & ~(size_t)255;
        return p;
    };
    // layout (~243 MB total; aliases annotated)
    u16*   Xb   = (u16*)  alloc((size_t)B * 4096 * 2);   // x bf16; L1-prep region after c0
    float* Tf   = (float*)alloc((size_t)B * 2048 * 4);   // pre-LN fp32
    u16*   Hb0  = (u16*)  alloc((size_t)B * 2048 * 2);
    u16*   Cb0  = (u16*)  alloc((size_t)B * 2048 * 2);   // c0 bf16; Gt0 during pre-pass
    u16*   rwb0 = (u16*)  alloc((size_t)2048 * 4096 * 2);
    u16*   DGt0 = (u16*)  alloc((size_t)2048 * 4096 * 2);// Hb1 after c0
    u16*   W0   = (u16*)  alloc((size_t)2048 * 2048 * 2);
    float* p20  = (float*)alloc(4096 * 4);
    float* p21  = (float*)alloc(2048 * 4);
    float* cv0  = (float*)alloc(2048 * 4);
    float* cv1  = (float*)alloc(1024 * 4);

    u16* Gt0 = Cb0;                       // [2048,4096] fits in Cb0
    u16* Hb1 = DGt0;                      // [8192,1024] == DGt0 size
    // L1 prep lives inside Xb after the c0 GEMM:
    char* l1 = (char*)Xb;
    u16* rwb1 = (u16*)l1;                 l1 += (size_t)1024 * 2048 * 2;
    u16* Gt1  = (u16*)l1;                 l1 += (size_t)1024 * 2048 * 2;
    u16* DGt1 = (u16*)l1;                 l1 += (size_t)1024 * 2048 * 2;
    u16* W1   = (u16*)l1;                 l1 += (size_t)1024 * 1024 * 2;
    u16* Cb1  = (u16*)l1;                 l1 += (size_t)B * 1024 * 2;

    auto cast = [&](const float* s, u16* d, size_t n) {
        int n4 = (int)(n >> 2);
        cast_bf16_kernel<<<dim3((n4 + 255) / 256), dim3(256), 0, stream>>>(
            (const float4*)s, (ushort4*)d, n4);
    };
    const dim3 blk(256);

    // ---- pre-pass (layer 0)
    prec2_kernel<<<dim3(16), blk, 0, stream>>>(log_p0, p20, 4096);
    prec2_kernel<<<dim3(8),  blk, 0, stream>>>(log_p1, p21, 2048);
    cast(x, Xb, (size_t)B * 4096);
    cast(rec_w0, rwb0, (size_t)2048 * 4096);
    transpose_cast_kernel<<<dim3(2048 / 32, 4096 / 32), blk, 0, stream>>>(
        gen_w0, Gt0, 4096, 2048, nullptr);           // Gt0[j][i] = G0[i][j]
    transpose_cast_kernel<<<dim3(2048 / 32, 4096 / 32), blk, 0, stream>>>(
        gen_w0, DGt0, 4096, 2048, p20);              // DGt0[j][i] = p2[i]*G0[i][j]
    cvec_kernel<<<dim3(2048 / 4), blk, 0, stream>>>(gen_b0, DGt0, cv0, 4096);
    // W0 = G0^T D G0  [2048,2048] bf16 (symmetric)
    gemm_bt<EPI_W><<<dim3(16, 16), blk, 0, stream>>>(
        Gt0, DGt0, 2048, 4096, nullptr, nullptr, nullptr, W0);

    // ---- layer 0 (in=4096, hid=2048)
    gemm_bt<EPI_BIAS><<<dim3(16, 64), blk, 0, stream>>>(
        Xb, rwb0, 2048, 4096, rec_b0, nullptr, nullptr, Tf);
    ln_kernel<0><<<dim3(B), blk, 0, stream>>>(Tf, ln_g0, ln_b0, Hb0, 2048);
    // c0 = x @ (D G0) - cv0   (last use of Xb, Gt0/Cb0 free after this writes)
    gemm_bt<EPI_CMB><<<dim3(16, 64), blk, 0, stream>>>(
        Xb, DGt0, 2048, 4096, cv0, nullptr, nullptr, Cb0);

    // ---- L1 prep (overwrites Xb region; DGt0 still live until here — done)
    cast(rec_w1, rwb1, (size_t)1024 * 2048);
    transpose_cast_kernel<<<dim3(1024 / 32, 2048 / 32), blk, 0, stream>>>(
        gen_w1, Gt1, 2048, 1024, nullptr);
    transpose_cast_kernel<<<dim3(1024 / 32, 2048 / 32), blk, 0, stream>>>(
        gen_w1, DGt1, 2048, 1024, p21);
    cvec_kernel<<<dim3(1024 / 4), blk, 0, stream>>>(gen_b1, DGt1, cv1, 2048);
    gemm_bt<EPI_W><<<dim3(8, 8), blk, 0, stream>>>(
        Gt1, DGt1, 1024, 2048, nullptr, nullptr, nullptr, W1);

    // ---- layer 0 iterations: T = h + 0.2*(c0 - h@W0); h = LN(T)
    for (int it = 0; it < 3; ++it) {
        gemm_bt<EPI_ITER><<<dim3(16, 64), blk, 0, stream>>>(
            Hb0, W0, 2048, 2048, nullptr, Cb0, Hb0, Tf);
        ln_kernel<0><<<dim3(B), blk, 0, stream>>>(Tf, ln_g0, ln_b0, Hb0, 2048);
    }

    // ---- layer 1 (in=2048, hid=1024); input = Hb0 (bf16)
    gemm_bt<EPI_BIAS><<<dim3(8, 64), blk, 0, stream>>>(
        Hb0, rwb1, 1024, 2048, rec_b1, nullptr, nullptr, Tf);
    ln_kernel<0><<<dim3(B), blk, 0, stream>>>(Tf, ln_g1, ln_b1, Hb1, 1024);
    gemm_bt<EPI_CMB><<<dim3(8, 64), blk, 0, stream>>>(
        Hb0, DGt1, 1024, 2048, cv1, nullptr, nullptr, Cb1);
    for (int it = 0; it < 3; ++it) {
        gemm_bt<EPI_ITER><<<dim3(8, 64), blk, 0, stream>>>(
            Hb1, W1, 1024, 1024, nullptr, Cb1, Hb1, Tf);
        if (it < 2)
            ln_kernel<0><<<dim3(B), blk, 0, stream>>>(Tf, ln_g1, ln_b1, Hb1, 1024);
        else
            ln_kernel<1><<<dim3(B), blk, 0, stream>>>(Tf, ln_g1, ln_b1, d_out, 1024);
    }
}